// Round 13
// baseline (91.208 us; speedup 1.0000x reference)
//
#include <hip/hip_runtime.h>

// Problem constants (fixed by setup_inputs)
#define B_   4
#define C_   256
#define H_   96
#define W_   128
#define F_   9
#define G_   4
#define CG   64            // channels per group
#define NC8  8             // channel OCTETS per group
#define NO   81            // offsets
#define HW_  (H_ * W_)

// One dy per pass (9 passes). Block = 4 out-rows x 128 cols, 2 px/thread.
#define OROWS 4
#define TCOLS 144                // 128 + 16 halo cols
#define PCOLS 72                 // cols per parity plane
#define NENT  (OROWS * 2 * PCOLS) // 576 16B-entries per buffer
#define PNK   3                  // staging chunks 256+256+64

typedef _Float16 half2v __attribute__((ext_vector_type(2)));
typedef unsigned u32x4 __attribute__((ext_vector_type(4)));

__device__ __forceinline__ half2v u2h(unsigned u) {
    half2v h; __builtin_memcpy(&h, &u, 4); return h;
}
__device__ __forceinline__ unsigned h2u(half2v h) {
    unsigned u; __builtin_memcpy(&u, &h, 4); return u;
}
__device__ __forceinline__ half2v pkrtz(float a, float b) {
    auto r = __builtin_amdgcn_cvt_pkrtz(a, b);
    half2v h; __builtin_memcpy(&h, &r, 4); return h;
}
__device__ __forceinline__ unsigned pkrtz_u(float a, float b) {
    auto r = __builtin_amdgcn_cvt_pkrtz(a, b);
    unsigned u; __builtin_memcpy(&u, &r, 4); return u;
}

#if __has_builtin(__builtin_amdgcn_fdot2)
#define FDOT2(a, b, c) __builtin_amdgcn_fdot2((a), (b), (c), false)
#else
__device__ __forceinline__ float fdot2_fb(half2v a, half2v b, float c) {
    return c + (float)a[0] * (float)b[0] + (float)a[1] * (float)b[1];
}
#define FDOT2(a, b, c) fdot2_fb((a), (b), (c))
#endif

// parity-plane col swizzle: bijective on [0,72), spreads stride-2 windows
__device__ __forceinline__ int swz(int col2) {
    return col2 ^ ((col2 >> 3) & 7);
}

// Pack weights [C,9,9] f32 -> [g][c8][o] as 8-channel (4x f16x2) in d_ws
__global__ void pack_weights_kernel(const float* __restrict__ w,
                                    u32x4* __restrict__ wp) {
    int i = blockIdx.x * blockDim.x + threadIdx.x;
    if (i >= G_ * NC8 * NO) return;
    int o  = i % NO;
    int c8 = (i / NO) % NC8;
    int g  = i / (NO * NC8);
    const float* base = w + (size_t)(g * CG + 8 * c8) * NO + o;
    u32x4 r;
    r.x = pkrtz_u(base[0 * NO], base[1 * NO]);
    r.y = pkrtz_u(base[2 * NO], base[3 * NO]);
    r.z = pkrtz_u(base[4 * NO], base[5 * NO]);
    r.w = pkrtz_u(base[6 * NO], base[7 * NO]);
    wp[i] = r;
}

template <bool PACKED>
__global__ __launch_bounds__(256)
void wcorr_kernel(const float* __restrict__ in1, const float* __restrict__ in2,
                  const u32x4* __restrict__ wp, const float* __restrict__ wraw,
                  float* __restrict__ out) {
    // entry = (row*2 + parity)*PCOLS + swz(col2)
    __shared__ u32x4 tile[2][NENT];   // 18,432 B

    // grid = 8 XCD x 48 tuples x 9 dy = 3456.  Round-robin dispatch: bid&7 =
    // XCD; dy innermost per tuple -> the 9 dy-blocks sharing in1 rows run
    // consecutively on the SAME XCD (R9-proven low FETCH).
    int bid   = blockIdx.x;
    int xcd   = bid & 7;
    int slot  = bid >> 3;               // 0..431
    int tuple = slot / 9;
    int dy    = slot - tuple * 9;       // 0..8
    int T     = tuple * 8 + xcd;        // 0..383
    int pair  = T & 15;                 // b*4+g
    int hblk  = T >> 4;                 // 0..23
    int b = pair >> 2, g = pair & 3;
    int h0 = hblk * OROWS;

    int t   = threadIdx.x;
    int row = t >> 6;                   // 0..3 (wave-uniform)
    int i   = t & 63;
    int j   = i >> 1;                   // 0..31
    int p   = i & 1;                    // parity
    const int c0 = 4 * j + p;           // px0 col; px1 = c0+2

    const float* in1g = in1 + (size_t)(b * C_ + g * CG) * HW_;
    const float* in2g = in2 + (size_t)(b * C_ + g * CG) * HW_;

    // ---- staging geometry (c8-invariant): clamp + mask, branchless ----
    const int gr0 = h0 + 2 * dy - 8;
    int po[PNK]; unsigned msk[PNK]; int lix[PNK];
#pragma unroll
    for (int k = 0; k < PNK; ++k) {
        int pidx = k * 256 + t;
        int srow = pidx / TCOLS;
        int col  = pidx - srow * TCOLS;
        int gr = gr0 + srow, gc = col - 8;
        bool inb = (pidx < NENT) && gr >= 0 && gr < H_ && gc >= 0 && gc < W_;
        int off = gr * W_ + gc;
        off = off < 0 ? 0 : (off > HW_ - 1 ? HW_ - 1 : off);
        po[k]  = off;
        float m = inb ? 1.f : 0.f;
        msk[k] = pkrtz_u(m, m);
        lix[k] = (srow * 2 + (col & 1)) * PCOLS + swz(col >> 1);
    }

    // window entry indices (c8-invariant): tap m -> entry widx[m]
    int widx[10];
#pragma unroll
    for (int m = 0; m < 10; ++m)
        widx[m] = (row * 2 + p) * PCOLS + swz(2 * j + m);

    float acc0[F_], acc1[F_];
#pragma unroll
    for (int dx = 0; dx < F_; ++dx) { acc0[dx] = 0.f; acc1[dx] = 0.f; }

    // staged in2 values for ONE tile, live across a full compute phase
    float sv[PNK][8];

    auto LOADS = [&](int c8n) {
        const float* chb = in2g + (size_t)(8 * c8n) * HW_;
#pragma unroll
        for (int k = 0; k < PNK; ++k) {
            if (k < PNK - 1 || t < NENT - (PNK - 1) * 256) {   // wave-uniform tail
                const float* q = chb + po[k];
#pragma unroll
                for (int c = 0; c < 8; ++c) sv[k][c] = q[(size_t)c * HW_];
            }
        }
    };
    auto WRITE = [&](u32x4* dst) {
#pragma unroll
        for (int k = 0; k < PNK; ++k) {
            if (k < PNK - 1 || t < NENT - (PNK - 1) * 256) {
                half2v m = u2h(msk[k]);
                u32x4 e;
                e.x = h2u(u2h(pkrtz_u(sv[k][0], sv[k][1])) * m);
                e.y = h2u(u2h(pkrtz_u(sv[k][2], sv[k][3])) * m);
                e.z = h2u(u2h(pkrtz_u(sv[k][4], sv[k][5])) * m);
                e.w = h2u(u2h(pkrtz_u(sv[k][6], sv[k][7])) * m);
                dst[lix[k]] = e;    // ds_write_b128, swizzled position
            }
        }
    };

    // ---- prologue: tile 0 staged; tile 1 loads in flight ----
    LOADS(0);
    WRITE(tile[0]);
    LOADS(1);

    const int in1off = (h0 + row) * W_ + c0;

    for (int c8 = 0; c8 < NC8; ++c8) {
        __syncthreads();   // tile[c8&1] readable; tile[(c8+1)&1] writable

        // write tile c8+1 (loads issued one FULL iteration ago -> vmcnt covered)
        if (c8 + 1 < NC8) WRITE(tile[(c8 + 1) & 1]);
        // issue loads for tile c8+2 (wait lands in NEXT iteration's WRITE)
        if (c8 + 2 < NC8) LOADS(c8 + 2);

        // in1 octets for both px (L1/L2-resident; latency covered by TLP)
        const float* ib = in1g + (size_t)(8 * c8) * HW_ + in1off;
        half2v ha0, ha1, ha2, ha3, hb0, hb1, hb2, hb3;
        {
            float x0 = ib[0], x1 = ib[HW_], x2 = ib[2 * HW_], x3 = ib[3 * HW_];
            float x4 = ib[4 * HW_], x5 = ib[5 * HW_], x6 = ib[6 * HW_], x7 = ib[7 * HW_];
            ha0 = pkrtz(x0, x1); ha1 = pkrtz(x2, x3);
            ha2 = pkrtz(x4, x5); ha3 = pkrtz(x6, x7);
            float y0 = ib[2], y1 = ib[HW_ + 2], y2 = ib[2 * HW_ + 2], y3 = ib[3 * HW_ + 2];
            float y4 = ib[4 * HW_ + 2], y5 = ib[5 * HW_ + 2], y6 = ib[6 * HW_ + 2], y7 = ib[7 * HW_ + 2];
            hb0 = pkrtz(y0, y1); hb1 = pkrtz(y2, y3);
            hb2 = pkrtz(y4, y5); hb3 = pkrtz(y6, y7);
        }

        const u32x4* lt = tile[c8 & 1];
        const u32x4* wrow = PACKED ? (wp + ((size_t)g * NC8 + c8) * NO + dy * F_) : nullptr;
        const float* wr = wraw + (size_t)(g * CG + 8 * c8) * NO + dy * F_;

        // one read per window entry; each feeds px0 (dx=m) and px1 (dx=m-1)
#pragma unroll
        for (int m = 0; m < 10; ++m) {
            u32x4 uv = lt[widx[m]];            // ds_read_b128
            if (m <= 8) {
                half2v w0h, w1h, w2h, w3h;
                if (PACKED) {
                    u32x4 wv = wrow[m];
                    w0h = u2h(wv.x); w1h = u2h(wv.y); w2h = u2h(wv.z); w3h = u2h(wv.w);
                } else {
                    w0h = pkrtz(wr[m + 0 * NO], wr[m + 1 * NO]);
                    w1h = pkrtz(wr[m + 2 * NO], wr[m + 3 * NO]);
                    w2h = pkrtz(wr[m + 4 * NO], wr[m + 5 * NO]);
                    w3h = pkrtz(wr[m + 6 * NO], wr[m + 7 * NO]);
                }
                float s = acc0[m];
                s = FDOT2(w0h * ha0, u2h(uv.x), s);
                s = FDOT2(w1h * ha1, u2h(uv.y), s);
                s = FDOT2(w2h * ha2, u2h(uv.z), s);
                s = FDOT2(w3h * ha3, u2h(uv.w), s);
                acc0[m] = s;
            }
            if (m >= 1) {
                const int dx = m - 1;
                half2v w0h, w1h, w2h, w3h;
                if (PACKED) {
                    u32x4 wv = wrow[dx];
                    w0h = u2h(wv.x); w1h = u2h(wv.y); w2h = u2h(wv.z); w3h = u2h(wv.w);
                } else {
                    w0h = pkrtz(wr[dx + 0 * NO], wr[dx + 1 * NO]);
                    w1h = pkrtz(wr[dx + 2 * NO], wr[dx + 3 * NO]);
                    w2h = pkrtz(wr[dx + 4 * NO], wr[dx + 5 * NO]);
                    w3h = pkrtz(wr[dx + 6 * NO], wr[dx + 7 * NO]);
                }
                float s = acc1[dx];
                s = FDOT2(w0h * hb0, u2h(uv.x), s);
                s = FDOT2(w1h * hb1, u2h(uv.y), s);
                s = FDOT2(w2h * hb2, u2h(uv.z), s);
                s = FDOT2(w3h * hb3, u2h(uv.w), s);
                acc1[dx] = s;
            }
        }
    }

    // out[b][g*81 + dy*9 + dx][h0+row][c0], [c0+2]
    size_t obase = (((size_t)(pair * NO + dy * F_)) * H_ + (h0 + row)) * W_ + c0;
#pragma unroll
    for (int dx = 0; dx < F_; ++dx) {
        out[obase + (size_t)dx * HW_]     = acc0[dx];
        out[obase + (size_t)dx * HW_ + 2] = acc1[dx];
    }
}

extern "C" void kernel_launch(void* const* d_in, const int* in_sizes, int n_in,
                              void* d_out, int out_size, void* d_ws, size_t ws_size,
                              hipStream_t stream) {
    const float* in1  = (const float*)d_in[0];
    const float* in2  = (const float*)d_in[1];
    const float* wraw = (const float*)d_in[2];
    float* out = (float*)d_out;

    const size_t wp_bytes = (size_t)G_ * NC8 * NO * 16;  // 41,472 B
    const int nblocks = 8 * 48 * F_;                     // 3456

    if (ws_size >= wp_bytes) {
        u32x4* wp = (u32x4*)d_ws;
        int n = G_ * NC8 * NO;
        pack_weights_kernel<<<(n + 255) / 256, 256, 0, stream>>>(wraw, wp);
        wcorr_kernel<true><<<nblocks, 256, 0, stream>>>(in1, in2, wp, wraw, out);
    } else {
        wcorr_kernel<false><<<nblocks, 256, 0, stream>>>(in1, in2, nullptr, wraw, out);
    }
}

// Round 14
// 90.090 us; speedup vs baseline: 1.0124x; 1.0124x over previous
//
#include <hip/hip_runtime.h>

// Problem constants (fixed by setup_inputs)
#define B_   4
#define C_   256
#define H_   96
#define W_   128
#define F_   9
#define G_   4
#define CG   64            // channels per group
#define NC8  8             // channel OCTETS per group
#define NO   81            // offsets
#define HW_  (H_ * W_)

// One dy per pass (9 passes). Block = 4 out-rows x 128 cols, 2 px/thread.
#define OROWS 4
#define TCOLS 144                // 128 + 16 halo cols
#define PCOLS 72                 // valid cols per parity plane
#define PSTR  73                 // PADDED plane stride (73 mod 8 = 1 -> conflict-free)
#define NENT  (OROWS * 2 * PSTR) // 584 16B-entries per buffer
#define NPIX  (OROWS * TCOLS)    // 576 halo pixels to stage
#define PNK   3                  // staging chunks 256+256+64

typedef _Float16 half2v __attribute__((ext_vector_type(2)));
typedef unsigned u32x4 __attribute__((ext_vector_type(4)));

__device__ __forceinline__ half2v u2h(unsigned u) {
    half2v h; __builtin_memcpy(&h, &u, 4); return h;
}
__device__ __forceinline__ unsigned h2u(half2v h) {
    unsigned u; __builtin_memcpy(&u, &h, 4); return u;
}
__device__ __forceinline__ half2v pkrtz(float a, float b) {
    auto r = __builtin_amdgcn_cvt_pkrtz(a, b);
    half2v h; __builtin_memcpy(&h, &r, 4); return h;
}
__device__ __forceinline__ unsigned pkrtz_u(float a, float b) {
    auto r = __builtin_amdgcn_cvt_pkrtz(a, b);
    unsigned u; __builtin_memcpy(&u, &r, 4); return u;
}

#if __has_builtin(__builtin_amdgcn_fdot2)
#define FDOT2(a, b, c) __builtin_amdgcn_fdot2((a), (b), (c), false)
#else
__device__ __forceinline__ float fdot2_fb(half2v a, half2v b, float c) {
    return c + (float)a[0] * (float)b[0] + (float)a[1] * (float)b[1];
}
#define FDOT2(a, b, c) fdot2_fb((a), (b), (c))
#endif

// Pack weights [C,9,9] f32 -> [g][c8][o] as 8-channel (4x f16x2) in d_ws
__global__ void pack_weights_kernel(const float* __restrict__ w,
                                    u32x4* __restrict__ wp) {
    int i = blockIdx.x * blockDim.x + threadIdx.x;
    if (i >= G_ * NC8 * NO) return;
    int o  = i % NO;
    int c8 = (i / NO) % NC8;
    int g  = i / (NO * NC8);
    const float* base = w + (size_t)(g * CG + 8 * c8) * NO + o;
    u32x4 r;
    r.x = pkrtz_u(base[0 * NO], base[1 * NO]);
    r.y = pkrtz_u(base[2 * NO], base[3 * NO]);
    r.z = pkrtz_u(base[4 * NO], base[5 * NO]);
    r.w = pkrtz_u(base[6 * NO], base[7 * NO]);
    wp[i] = r;
}

template <bool PACKED>
__global__ __launch_bounds__(256)
void wcorr_kernel(const float* __restrict__ in1, const float* __restrict__ in2,
                  const u32x4* __restrict__ wp, const float* __restrict__ wraw,
                  float* __restrict__ out) {
    // entry = (row*2 + parity)*PSTR + col2  (padded stride, NO swizzle)
    __shared__ u32x4 tile[2][NENT];   // 18,688 B

    // grid = 8 XCD x 48 tuples x 9 dy = 3456.  Round-robin dispatch: bid&7 =
    // XCD; dy innermost per tuple -> the 9 dy-blocks sharing in1 rows run
    // consecutively on the SAME XCD (R9/R13-proven low FETCH).
    int bid   = blockIdx.x;
    int xcd   = bid & 7;
    int slot  = bid >> 3;               // 0..431
    int tuple = slot / 9;
    int dy    = slot - tuple * 9;       // 0..8
    int T     = tuple * 8 + xcd;        // 0..383
    int pair  = T & 15;                 // b*4+g
    int hblk  = T >> 4;                 // 0..23
    int b = pair >> 2, g = pair & 3;
    int h0 = hblk * OROWS;

    int t   = threadIdx.x;
    int row = t >> 6;                   // 0..3 (wave-uniform)
    int i   = t & 63;
    int j   = i >> 1;                   // 0..31
    int p   = i & 1;                    // parity
    const int c0 = 4 * j + p;           // px0 col; px1 = c0+2

    const float* in1g = in1 + (size_t)(b * C_ + g * CG) * HW_;
    const float* in2g = in2 + (size_t)(b * C_ + g * CG) * HW_;

    // ---- staging geometry (c8-invariant): clamp + mask, branchless ----
    const int gr0 = h0 + 2 * dy - 8;
    int po[PNK]; unsigned msk[PNK]; int lix[PNK];
#pragma unroll
    for (int k = 0; k < PNK; ++k) {
        int pidx = k * 256 + t;
        int srow = pidx / TCOLS;
        int col  = pidx - srow * TCOLS;
        int gr = gr0 + srow, gc = col - 8;
        bool inb = (pidx < NPIX) && gr >= 0 && gr < H_ && gc >= 0 && gc < W_;
        int off = gr * W_ + gc;
        off = off < 0 ? 0 : (off > HW_ - 1 ? HW_ - 1 : off);
        po[k]  = off;
        float m = inb ? 1.f : 0.f;
        msk[k] = pkrtz_u(m, m);
        lix[k] = (srow * 2 + (col & 1)) * PSTR + (col >> 1);
    }

    float acc0[F_], acc1[F_];
#pragma unroll
    for (int dx = 0; dx < F_; ++dx) { acc0[dx] = 0.f; acc1[dx] = 0.f; }

    // staged in2 values for ONE tile, live across a full compute phase
    float sv[PNK][8];

    auto LOADS = [&](int c8n) {
        const float* chb = in2g + (size_t)(8 * c8n) * HW_;
#pragma unroll
        for (int k = 0; k < PNK; ++k) {
            if (k < PNK - 1 || t < NPIX - (PNK - 1) * 256) {
                const float* q = chb + po[k];
#pragma unroll
                for (int c = 0; c < 8; ++c) sv[k][c] = q[(size_t)c * HW_];
            }
        }
    };
    auto WRITE = [&](u32x4* dst) {
#pragma unroll
        for (int k = 0; k < PNK; ++k) {
            if (k < PNK - 1 || t < NPIX - (PNK - 1) * 256) {
                half2v m = u2h(msk[k]);
                u32x4 e;
                e.x = h2u(u2h(pkrtz_u(sv[k][0], sv[k][1])) * m);
                e.y = h2u(u2h(pkrtz_u(sv[k][2], sv[k][3])) * m);
                e.z = h2u(u2h(pkrtz_u(sv[k][4], sv[k][5])) * m);
                e.w = h2u(u2h(pkrtz_u(sv[k][6], sv[k][7])) * m);
                dst[lix[k]] = e;    // ds_write_b128 (uniform 8 lanes/bank-quad)
            }
        }
    };

    // ---- prologue: tile 0 staged; tile 1 loads in flight; in1 octet 0 ----
    LOADS(0);
    WRITE(tile[0]);
    LOADS(1);

    const int in1off = (h0 + row) * W_ + c0;
    float a[16];
    {
        const float* ib = in1g + in1off;
#pragma unroll
        for (int c = 0; c < 8; ++c) {
            a[c]     = ib[(size_t)c * HW_];
            a[8 + c] = ib[(size_t)c * HW_ + 2];
        }
    }

    // per-lane window base (entry units); tap m = wb + m, compile-time m
    const int wb = (row * 2 + p) * PSTR + 2 * j;

    for (int c8 = 0; c8 < NC8; ++c8) {
        __syncthreads();   // tile[c8&1] readable; tile[(c8+1)&1] writable

        // write tile c8+1 (loads issued one FULL iteration ago -> vmcnt covered)
        if (c8 + 1 < NC8) WRITE(tile[(c8 + 1) & 1]);
        // issue loads for tile c8+2 (wait lands in NEXT iteration's WRITE)
        if (c8 + 2 < NC8) LOADS(c8 + 2);

        // pack current in1 octets, then prefetch next into the same regs
        half2v ha0 = pkrtz(a[0], a[1]),  ha1 = pkrtz(a[2], a[3]);
        half2v ha2 = pkrtz(a[4], a[5]),  ha3 = pkrtz(a[6], a[7]);
        half2v hb0 = pkrtz(a[8], a[9]),  hb1 = pkrtz(a[10], a[11]);
        half2v hb2 = pkrtz(a[12], a[13]), hb3 = pkrtz(a[14], a[15]);
        if (c8 + 1 < NC8) {
            const float* ib = in1g + (size_t)(8 * (c8 + 1)) * HW_ + in1off;
#pragma unroll
            for (int c = 0; c < 8; ++c) {
                a[c]     = ib[(size_t)c * HW_];
                a[8 + c] = ib[(size_t)c * HW_ + 2];
            }
        }

        const u32x4* lt = tile[c8 & 1] + wb;
        const u32x4* wrow = PACKED ? (wp + ((size_t)g * NC8 + c8) * NO + dy * F_) : nullptr;
        const float* wr = wraw + (size_t)(g * CG + 8 * c8) * NO + dy * F_;

        // one b128 read per window entry (imm offset); entry m feeds
        // px0 (dx=m, m<=8) and px1 (dx=m-1, m>=1)
#pragma unroll
        for (int m = 0; m < 10; ++m) {
            u32x4 uv = lt[m];                   // ds_read_b128 offset:16*m
            if (m <= 8) {
                half2v w0h, w1h, w2h, w3h;
                if (PACKED) {
                    u32x4 wv = wrow[m];
                    w0h = u2h(wv.x); w1h = u2h(wv.y); w2h = u2h(wv.z); w3h = u2h(wv.w);
                } else {
                    w0h = pkrtz(wr[m + 0 * NO], wr[m + 1 * NO]);
                    w1h = pkrtz(wr[m + 2 * NO], wr[m + 3 * NO]);
                    w2h = pkrtz(wr[m + 4 * NO], wr[m + 5 * NO]);
                    w3h = pkrtz(wr[m + 6 * NO], wr[m + 7 * NO]);
                }
                float s = acc0[m];
                s = FDOT2(w0h * ha0, u2h(uv.x), s);
                s = FDOT2(w1h * ha1, u2h(uv.y), s);
                s = FDOT2(w2h * ha2, u2h(uv.z), s);
                s = FDOT2(w3h * ha3, u2h(uv.w), s);
                acc0[m] = s;
            }
            if (m >= 1) {
                const int dx = m - 1;
                half2v w0h, w1h, w2h, w3h;
                if (PACKED) {
                    u32x4 wv = wrow[dx];
                    w0h = u2h(wv.x); w1h = u2h(wv.y); w2h = u2h(wv.z); w3h = u2h(wv.w);
                } else {
                    w0h = pkrtz(wr[dx + 0 * NO], wr[dx + 1 * NO]);
                    w1h = pkrtz(wr[dx + 2 * NO], wr[dx + 3 * NO]);
                    w2h = pkrtz(wr[dx + 4 * NO], wr[dx + 5 * NO]);
                    w3h = pkrtz(wr[dx + 6 * NO], wr[dx + 7 * NO]);
                }
                float s = acc1[dx];
                s = FDOT2(w0h * hb0, u2h(uv.x), s);
                s = FDOT2(w1h * hb1, u2h(uv.y), s);
                s = FDOT2(w2h * hb2, u2h(uv.z), s);
                s = FDOT2(w3h * hb3, u2h(uv.w), s);
                acc1[dx] = s;
            }
        }
    }

    // out[b][g*81 + dy*9 + dx][h0+row][c0], [c0+2]
    size_t obase = (((size_t)(pair * NO + dy * F_)) * H_ + (h0 + row)) * W_ + c0;
#pragma unroll
    for (int dx = 0; dx < F_; ++dx) {
        out[obase + (size_t)dx * HW_]     = acc0[dx];
        out[obase + (size_t)dx * HW_ + 2] = acc1[dx];
    }
}

extern "C" void kernel_launch(void* const* d_in, const int* in_sizes, int n_in,
                              void* d_out, int out_size, void* d_ws, size_t ws_size,
                              hipStream_t stream) {
    const float* in1  = (const float*)d_in[0];
    const float* in2  = (const float*)d_in[1];
    const float* wraw = (const float*)d_in[2];
    float* out = (float*)d_out;

    const size_t wp_bytes = (size_t)G_ * NC8 * NO * 16;  // 41,472 B
    const int nblocks = 8 * 48 * F_;                     // 3456

    if (ws_size >= wp_bytes) {
        u32x4* wp = (u32x4*)d_ws;
        int n = G_ * NC8 * NO;
        pack_weights_kernel<<<(n + 255) / 256, 256, 0, stream>>>(wraw, wp);
        wcorr_kernel<true><<<nblocks, 256, 0, stream>>>(in1, in2, wp, wraw, out);
    } else {
        wcorr_kernel<false><<<nblocks, 256, 0, stream>>>(in1, in2, nullptr, wraw, out);
    }
}

// Round 15
// 77.630 us; speedup vs baseline: 1.1749x; 1.1605x over previous
//
#include <hip/hip_runtime.h>

// Problem constants (fixed by setup_inputs)
#define B_   4
#define C_   256
#define H_   96
#define W_   128
#define F_   9
#define G_   4
#define CG   64            // channels per group
#define NC8  8             // channel OCTETS per group
#define NO   81            // offsets
#define HW_  (H_ * W_)

// Block 256 = 4 waves; wave r owns output row h0+r, 64 cols; 3 dy per pass.
// Wave-PRIVATE LDS: 3 tap planes x 80 cols, double-buffered. NO barriers.
#define NDY   3
#define OROWS 4
#define TCOLS 80                 // 64 + 16 halo cols
#define WENT  (NDY * TCOLS)      // 240 16B-entries per wave-buffer
#define NPRC  (NDY * 40)         // 120 col-pairs per wave tile

typedef _Float16 half2v __attribute__((ext_vector_type(2)));
typedef unsigned u32x4 __attribute__((ext_vector_type(4)));
typedef float    f32x2 __attribute__((ext_vector_type(2)));

__device__ __forceinline__ half2v u2h(unsigned u) {
    half2v h; __builtin_memcpy(&h, &u, 4); return h;
}
__device__ __forceinline__ unsigned h2u(half2v h) {
    unsigned u; __builtin_memcpy(&u, &h, 4); return u;
}
__device__ __forceinline__ half2v pkrtz(float a, float b) {
    auto r = __builtin_amdgcn_cvt_pkrtz(a, b);
    half2v h; __builtin_memcpy(&h, &r, 4); return h;
}
__device__ __forceinline__ unsigned pkrtz_u(float a, float b) {
    auto r = __builtin_amdgcn_cvt_pkrtz(a, b);
    unsigned u; __builtin_memcpy(&u, &r, 4); return u;
}

#if __has_builtin(__builtin_amdgcn_fdot2)
#define FDOT2(a, b, c) __builtin_amdgcn_fdot2((a), (b), (c), false)
#else
__device__ __forceinline__ float fdot2_fb(half2v a, half2v b, float c) {
    return c + (float)a[0] * (float)b[0] + (float)a[1] * (float)b[1];
}
#define FDOT2(a, b, c) fdot2_fb((a), (b), (c))
#endif

// Pack weights [C,9,9] f32 -> [g][c8][o] as 8-channel (4x f16x2) in d_ws
__global__ void pack_weights_kernel(const float* __restrict__ w,
                                    u32x4* __restrict__ wp) {
    int i = blockIdx.x * blockDim.x + threadIdx.x;
    if (i >= G_ * NC8 * NO) return;
    int o  = i % NO;
    int c8 = (i / NO) % NC8;
    int g  = i / (NO * NC8);
    const float* base = w + (size_t)(g * CG + 8 * c8) * NO + o;
    u32x4 r;
    r.x = pkrtz_u(base[0 * NO], base[1 * NO]);
    r.y = pkrtz_u(base[2 * NO], base[3 * NO]);
    r.z = pkrtz_u(base[4 * NO], base[5 * NO]);
    r.w = pkrtz_u(base[6 * NO], base[7 * NO]);
    wp[i] = r;
}

template <bool PACKED>
__global__ __launch_bounds__(256)
void wcorr_kernel(const float* __restrict__ in1, const float* __restrict__ in2,
                  const u32x4* __restrict__ wp, const float* __restrict__ wraw,
                  float* __restrict__ out) {
    // [wave][buf][WENT] : 4*2*240 entries * 16B = 30,720 B
    __shared__ u32x4 tile[OROWS * 2 * WENT];

    // grid = 2304: 16 pairs x {3 pass x 24 hblk x 2 half}  (R11 mapping)
    int bid  = blockIdx.x;
    int xcd  = bid & 7;
    int slot = bid >> 3;                 // 0..287
    int pair = xcd + 8 * (slot / 144);   // 0..15  == b*4+g
    int rem  = slot % 144;
    int pass = rem / 48;                 // 0..2  (dy block)
    int sub  = rem % 48;
    int hblk = sub >> 1;                 // 0..23
    int half = sub & 1;                  // col half
    int b = pair >> 2, g = pair & 3;
    int h0 = hblk * OROWS;
    int w0 = half * 64;

    int t = threadIdx.x;
    int r = t >> 6;                 // wave id = output row offset
    int x = t & 63;                 // lane = output col within half

    const float* in1g = in1 + (size_t)(b * C_ + g * CG) * HW_;
    const float* in2g = in2 + (size_t)(b * C_ + g * CG) * HW_;

    // ---- wave-private staging geometry (c8-invariant) ----
    // wave r taps global rows gr0+r+2*dyp; plane dyp, cols gc0..gc0+79
    const int gr0 = h0 - 8 + 6 * pass;
    const int gc0 = w0 - 8;              // even -> 8B-aligned pair loads
    int po[2]; unsigned mA[2], mB[2]; int lix[2];
#pragma unroll
    for (int k = 0; k < 2; ++k) {
        int pi = k * 64 + x;             // col-pair index, valid < NPRC
        int pl = pi / 40;                // plane
        int pc = pi - 40 * pl;           // pair col
        int gr = gr0 + r + 2 * pl;
        int gc = gc0 + 2 * pc;
        bool grv = (pi < NPRC) && gr >= 0 && gr < H_;
        float f0 = (grv && gc >= 0 && gc < W_) ? 1.f : 0.f;
        float f1 = (grv && gc + 1 >= 0 && gc + 1 < W_) ? 1.f : 0.f;
        int off = gr * W_ + gc;
        off = off < 0 ? 0 : (off > HW_ - 2 ? HW_ - 2 : off);
        po[k] = off;                     // even -> 8B aligned
        mA[k] = pkrtz_u(f0, f0);
        mB[k] = pkrtz_u(f1, f1);
        lix[k] = pl * TCOLS + 2 * pc;
    }

    float acc[NDY * F_];
#pragma unroll
    for (int o = 0; o < NDY * F_; ++o) acc[o] = 0.f;

    // staged in2 col-pairs for ONE tile (8 ch x 2 chunks), live across compute
    f32x2 sv[2][8];

    auto LOADS = [&](int c8n) {
        const float* chb = in2g + (size_t)(8 * c8n) * HW_;
#pragma unroll
        for (int k = 0; k < 2; ++k) {
            const float* q = chb + po[k];
#pragma unroll
            for (int j = 0; j < 8; ++j)
                sv[k][j] = *(const f32x2*)(q + (size_t)j * HW_);
        }
    };
    auto WRITE = [&](int buf) {
        u32x4* wt = tile + (r * 2 + buf) * WENT;
#pragma unroll
        for (int k = 0; k < 2; ++k) {
            if (k == 0 || x < NPRC - 64) {   // lane-guard chunk 1 (x<56)
                half2v m0 = u2h(mA[k]), m1 = u2h(mB[k]);
                u32x4 e0, e1;
                e0.x = h2u(u2h(pkrtz_u(sv[k][0].x, sv[k][1].x)) * m0);
                e0.y = h2u(u2h(pkrtz_u(sv[k][2].x, sv[k][3].x)) * m0);
                e0.z = h2u(u2h(pkrtz_u(sv[k][4].x, sv[k][5].x)) * m0);
                e0.w = h2u(u2h(pkrtz_u(sv[k][6].x, sv[k][7].x)) * m0);
                e1.x = h2u(u2h(pkrtz_u(sv[k][0].y, sv[k][1].y)) * m1);
                e1.y = h2u(u2h(pkrtz_u(sv[k][2].y, sv[k][3].y)) * m1);
                e1.z = h2u(u2h(pkrtz_u(sv[k][4].y, sv[k][5].y)) * m1);
                e1.w = h2u(u2h(pkrtz_u(sv[k][6].y, sv[k][7].y)) * m1);
                wt[lix[k]]     = e0;     // ds_write_b128 x2 (32B/lane)
                wt[lix[k] + 1] = e1;
            }
        }
    };

    // ---- prologue: tile 0 staged; tile 1 loads in flight; in1 octet 0 ----
    LOADS(0);
    WRITE(0);
    LOADS(1);

    const int in1off = (h0 + r) * W_ + (w0 + x);
    float a[8];
#pragma unroll
    for (int j = 0; j < 8; ++j) a[j] = in1g[in1off + (size_t)j * HW_];

    for (int c8 = 0; c8 < NC8; ++c8) {
        // NO barrier: wave-private buffers, same-wave DS ordering suffices.
        if (c8 + 1 < NC8) WRITE((c8 + 1) & 1);  // sv holds c8+1 (dist-2 loads)
        if (c8 + 2 < NC8) LOADS(c8 + 2);        // wait lands next iter's WRITE

        half2v ha0 = pkrtz(a[0], a[1]), ha1 = pkrtz(a[2], a[3]);
        half2v ha2 = pkrtz(a[4], a[5]), ha3 = pkrtz(a[6], a[7]);
        if (c8 + 1 < NC8) {                     // prefetch next in1 octet
            const float* ib = in1g + (size_t)(8 * (c8 + 1)) * HW_ + in1off;
#pragma unroll
            for (int j = 0; j < 8; ++j) a[j] = ib[(size_t)j * HW_];
        }

        const u32x4* lb = tile + (r * 2 + (c8 & 1)) * WENT + x;
        const u32x4* wrow = PACKED ? (wp + ((size_t)g * NC8 + c8) * NO + pass * NDY * F_) : nullptr;
        const float* wr = wraw + (size_t)(g * CG + 8 * c8) * NO + pass * NDY * F_;

#pragma unroll
        for (int dyp = 0; dyp < NDY; ++dyp) {
#pragma unroll
            for (int dx = 0; dx < F_; ++dx) {
                const int oo = dyp * F_ + dx;
                u32x4 uv = lb[dyp * TCOLS + 2 * dx];  // ds_read_b128, imm offset
                half2v w0h, w1h, w2h, w3h;
                if (PACKED) {
                    u32x4 wv = wrow[oo];              // wave-uniform -> s_load
                    w0h = u2h(wv.x); w1h = u2h(wv.y);
                    w2h = u2h(wv.z); w3h = u2h(wv.w);
                } else {
                    w0h = pkrtz(wr[oo + 0 * NO], wr[oo + 1 * NO]);
                    w1h = pkrtz(wr[oo + 2 * NO], wr[oo + 3 * NO]);
                    w2h = pkrtz(wr[oo + 4 * NO], wr[oo + 5 * NO]);
                    w3h = pkrtz(wr[oo + 6 * NO], wr[oo + 7 * NO]);
                }
                float s = acc[oo];
                s = FDOT2(w0h * ha0, u2h(uv.x), s);
                s = FDOT2(w1h * ha1, u2h(uv.y), s);
                s = FDOT2(w2h * ha2, u2h(uv.z), s);
                s = FDOT2(w3h * ha3, u2h(uv.w), s);
                acc[oo] = s;
            }
        }
    }

    // out[b][g*81 + pass*27 + oo][h0+r][w0+x]
    size_t obase = (((size_t)pair * NO + pass * NDY * F_) * H_ + (h0 + r)) * W_ + (w0 + x);
#pragma unroll
    for (int oo = 0; oo < NDY * F_; ++oo)
        out[obase + (size_t)oo * HW_] = acc[oo];
}

extern "C" void kernel_launch(void* const* d_in, const int* in_sizes, int n_in,
                              void* d_out, int out_size, void* d_ws, size_t ws_size,
                              hipStream_t stream) {
    const float* in1  = (const float*)d_in[0];
    const float* in2  = (const float*)d_in[1];
    const float* wraw = (const float*)d_in[2];
    float* out = (float*)d_out;

    const size_t wp_bytes = (size_t)G_ * NC8 * NO * 16;  // 41,472 B
    const int nblocks = 16 * 3 * 24 * 2;                 // 2304

    if (ws_size >= wp_bytes) {
        u32x4* wp = (u32x4*)d_ws;
        int n = G_ * NC8 * NO;
        pack_weights_kernel<<<(n + 255) / 256, 256, 0, stream>>>(wraw, wp);
        wcorr_kernel<true><<<nblocks, 256, 0, stream>>>(in1, in2, wp, wraw, out);
    } else {
        wcorr_kernel<false><<<nblocks, 256, 0, stream>>>(in1, in2, nullptr, wraw, out);
    }
}

// Round 16
// 75.154 us; speedup vs baseline: 1.2136x; 1.0329x over previous
//
#include <hip/hip_runtime.h>

// Problem constants (fixed by setup_inputs)
#define B_   4
#define C_   256
#define H_   96
#define W_   128
#define F_   9
#define G_   4
#define CG   64            // channels per group
#define NC8  8             // channel OCTETS per group
#define NO   81            // offsets
#define HW_  (H_ * W_)

// Block: 256 thr = 4 out-rows x 64 cols (half width); 3 dy per pass (R11 shape)
#define NDY   3
#define OROWS 4
#define TROWS 12                 // tap rows: r + 2*dyp, r=0..3, dyp=0..2 -> 0..7? (R11: 8)
#undef TROWS
#define TROWS 8                  // r 0..3 + 2*dyp 0..2 -> rows 0..7
#define TCOLS 80                 // 64 + 16 halo cols
#define PTE   (TROWS * TCOLS)    // 640 entries (16B: 8ch f16)
#define PNK   3                  // staging chunks 256+256+128
#define NWO   (NC8 * NDY * F_)   // 216 weight entries in LDS

typedef _Float16 half2v __attribute__((ext_vector_type(2)));
typedef unsigned u32x4 __attribute__((ext_vector_type(4)));

__device__ __forceinline__ half2v u2h(unsigned u) {
    half2v h; __builtin_memcpy(&h, &u, 4); return h;
}
__device__ __forceinline__ unsigned h2u(half2v h) {
    unsigned u; __builtin_memcpy(&u, &h, 4); return u;
}
__device__ __forceinline__ half2v pkrtz(float a, float b) {
    auto r = __builtin_amdgcn_cvt_pkrtz(a, b);
    half2v h; __builtin_memcpy(&h, &r, 4); return h;
}
__device__ __forceinline__ unsigned pkrtz_u(float a, float b) {
    auto r = __builtin_amdgcn_cvt_pkrtz(a, b);
    unsigned u; __builtin_memcpy(&u, &r, 4); return u;
}

#if __has_builtin(__builtin_amdgcn_fdot2)
#define FDOT2(a, b, c) __builtin_amdgcn_fdot2((a), (b), (c), false)
#else
__device__ __forceinline__ float fdot2_fb(half2v a, half2v b, float c) {
    return c + (float)a[0] * (float)b[0] + (float)a[1] * (float)b[1];
}
#define FDOT2(a, b, c) fdot2_fb((a), (b), (c))
#endif

// Pack weights [C,9,9] f32 -> [g][c8][o] as 8-channel (4x f16x2) in d_ws
__global__ void pack_weights_kernel(const float* __restrict__ w,
                                    u32x4* __restrict__ wp) {
    int i = blockIdx.x * blockDim.x + threadIdx.x;
    if (i >= G_ * NC8 * NO) return;
    int o  = i % NO;
    int c8 = (i / NO) % NC8;
    int g  = i / (NO * NC8);
    const float* base = w + (size_t)(g * CG + 8 * c8) * NO + o;
    u32x4 r;
    r.x = pkrtz_u(base[0 * NO], base[1 * NO]);
    r.y = pkrtz_u(base[2 * NO], base[3 * NO]);
    r.z = pkrtz_u(base[4 * NO], base[5 * NO]);
    r.w = pkrtz_u(base[6 * NO], base[7 * NO]);
    wp[i] = r;
}

template <bool PACKED>
__global__ __launch_bounds__(256)
void wcorr_kernel(const float* __restrict__ in1, const float* __restrict__ in2,
                  const u32x4* __restrict__ wp, const float* __restrict__ wraw,
                  float* __restrict__ out) {
    __shared__ u32x4 tile[2][PTE];   // 20,480 B
    __shared__ u32x4 wlds[NWO];      // 3,456 B — block's weight slice, staged once

    // grid = 2304: 16 pairs x {3 pass x 24 hblk x 2 half}  (R11 mapping)
    int bid  = blockIdx.x;
    int xcd  = bid & 7;
    int slot = bid >> 3;                 // 0..287
    int pair = xcd + 8 * (slot / 144);   // 0..15  == b*4+g
    int rem  = slot % 144;
    int pass = rem / 48;                 // 0..2  (dy block)
    int sub  = rem % 48;
    int hblk = sub >> 1;                 // 0..23
    int half = sub & 1;                  // col half
    int b = pair >> 2, g = pair & 3;
    int h0 = hblk * OROWS;
    int w0 = half * 64;

    int t = threadIdx.x;
    int r = t >> 6;                 // 0..3 output row (uniform per wave)
    int x = t & 63;                 // 0..63 output col within half

    const float* in1g = in1 + (size_t)(b * C_ + g * CG) * HW_;
    const float* in2g = in2 + (size_t)(b * C_ + g * CG) * HW_;

    // ---- stage the whole weight slice into LDS (once; covered by 1st barrier)
    if (t < NWO) {
        int c8s = t / 27;
        int oo  = t - 27 * c8s;
        if (PACKED) {
            wlds[t] = wp[((size_t)(g * NC8 + c8s)) * NO + pass * 27 + oo];
        } else {
            const float* base = wraw + (size_t)(g * CG + 8 * c8s) * NO + pass * 27 + oo;
            u32x4 e;
            e.x = pkrtz_u(base[0 * NO], base[1 * NO]);
            e.y = pkrtz_u(base[2 * NO], base[3 * NO]);
            e.z = pkrtz_u(base[4 * NO], base[5 * NO]);
            e.w = pkrtz_u(base[6 * NO], base[7 * NO]);
            wlds[t] = e;
        }
    }

    // ---- staging geometry (c8-invariant): clamp + mask, branchless ----
    const int gr0 = h0 - 8 + 6 * pass;
    const int gc0 = w0 - 8;
    int po[PNK]; unsigned msk[PNK];
#pragma unroll
    for (int k = 0; k < PNK; ++k) {
        int pidx = k * 256 + t;
        int row  = pidx / TCOLS;
        int col  = pidx - row * TCOLS;
        int gr = gr0 + row, gc = gc0 + col;
        bool inb = (pidx < PTE) && gr >= 0 && gr < H_ && gc >= 0 && gc < W_;
        int off = gr * W_ + gc;
        off = off < 0 ? 0 : (off > HW_ - 1 ? HW_ - 1 : off);
        po[k]  = off;
        float m = inb ? 1.f : 0.f;
        msk[k] = pkrtz_u(m, m);
    }

    float acc[NDY * F_];
#pragma unroll
    for (int o = 0; o < NDY * F_; ++o) acc[o] = 0.f;

    // staged in2 values for ONE tile (8 ch x PNK chunks), live across compute
    float sv[PNK][8];

    auto LOADS = [&](int c8n) {
        const float* chb = in2g + (size_t)(8 * c8n) * HW_;
#pragma unroll
        for (int k = 0; k < PNK; ++k) {
            const float* q = chb + po[k];
#pragma unroll
            for (int j = 0; j < 8; ++j) sv[k][j] = q[(size_t)j * HW_];
        }
    };
    auto WRITE = [&](u32x4* dst) {
#pragma unroll
        for (int k = 0; k < PNK; ++k) {
            if (k < PNK - 1 || t < PTE - (PNK - 1) * 256) {
                half2v m = u2h(msk[k]);
                u32x4 e;
                e.x = h2u(u2h(pkrtz_u(sv[k][0], sv[k][1])) * m);
                e.y = h2u(u2h(pkrtz_u(sv[k][2], sv[k][3])) * m);
                e.z = h2u(u2h(pkrtz_u(sv[k][4], sv[k][5])) * m);
                e.w = h2u(u2h(pkrtz_u(sv[k][6], sv[k][7])) * m);
                dst[k * 256 + t] = e;    // ds_write_b128, contiguous
            }
        }
    };

    // ---- prologue: tile 0 staged; tile 1 loads in flight ----
    LOADS(0);
    WRITE(tile[0]);
    LOADS(1);

    const int in1off = (h0 + r) * W_ + (w0 + x);
    float a[8];
#pragma unroll
    for (int j = 0; j < 8; ++j) a[j] = in1g[in1off + (size_t)j * HW_];

    for (int c8 = 0; c8 < NC8; ++c8) {
        __syncthreads();   // tile[c8&1] readable (+ wlds on 1st iter)

        // write tile c8+1 (loads issued one FULL iteration ago -> vmcnt covered)
        if (c8 + 1 < NC8) WRITE(tile[(c8 + 1) & 1]);
        // issue loads for tile c8+2 (wait lands in NEXT iteration's WRITE)
        if (c8 + 2 < NC8) LOADS(c8 + 2);

        // pack current in1, then prefetch next octet into the same floats
        half2v ha0 = pkrtz(a[0], a[1]), ha1 = pkrtz(a[2], a[3]);
        half2v ha2 = pkrtz(a[4], a[5]), ha3 = pkrtz(a[6], a[7]);
        if (c8 + 1 < NC8) {
            const float* pp = in1g + (size_t)(8 * (c8 + 1)) * HW_ + in1off;
#pragma unroll
            for (int j = 0; j < 8; ++j) a[j] = pp[(size_t)j * HW_];
        }

        const u32x4* lt = tile[c8 & 1];
        const u32x4* wl = wlds + c8 * (NDY * F_);   // uniform base; pure-DS fetches

#pragma unroll
        for (int dyp = 0; dyp < NDY; ++dyp) {
            const u32x4* rowp = lt + (r + 2 * dyp) * TCOLS + x;
#pragma unroll
            for (int dx = 0; dx < F_; ++dx) {
                const int oo = dyp * F_ + dx;
                u32x4 uv = rowp[2 * dx];            // ds_read_b128, imm offset
                u32x4 wv = wl[oo];                  // ds_read_b128 broadcast (uniform addr)
                half2v w0h = u2h(wv.x), w1h = u2h(wv.y);
                half2v w2h = u2h(wv.z), w3h = u2h(wv.w);
                float s = acc[oo];
                s = FDOT2(w0h * ha0, u2h(uv.x), s);
                s = FDOT2(w1h * ha1, u2h(uv.y), s);
                s = FDOT2(w2h * ha2, u2h(uv.z), s);
                s = FDOT2(w3h * ha3, u2h(uv.w), s);
                acc[oo] = s;
            }
        }
    }

    // out[b][g*81 + pass*27 + oo][h0+r][w0+x]
    size_t obase = (((size_t)pair * NO + pass * NDY * F_) * H_ + (h0 + r)) * W_ + (w0 + x);
#pragma unroll
    for (int oo = 0; oo < NDY * F_; ++oo)
        out[obase + (size_t)oo * HW_] = acc[oo];
}

extern "C" void kernel_launch(void* const* d_in, const int* in_sizes, int n_in,
                              void* d_out, int out_size, void* d_ws, size_t ws_size,
                              hipStream_t stream) {
    const float* in1  = (const float*)d_in[0];
    const float* in2  = (const float*)d_in[1];
    const float* wraw = (const float*)d_in[2];
    float* out = (float*)d_out;

    const size_t wp_bytes = (size_t)G_ * NC8 * NO * 16;  // 41,472 B
    const int nblocks = 16 * 3 * 24 * 2;                 // 2304

    if (ws_size >= wp_bytes) {
        u32x4* wp = (u32x4*)d_ws;
        int n = G_ * NC8 * NO;
        pack_weights_kernel<<<(n + 255) / 256, 256, 0, stream>>>(wraw, wp);
        wcorr_kernel<true><<<nblocks, 256, 0, stream>>>(in1, in2, wp, wraw, out);
    } else {
        wcorr_kernel<false><<<nblocks, 256, 0, stream>>>(in1, in2, nullptr, wraw, out);
    }
}